// Round 1
// baseline (143.846 us; speedup 1.0000x reference)
//
#include <hip/hip_runtime.h>

#define NB     64          // batch
#define HH     512
#define WW     512
#define HWSZ   (HH * WW)   // 262144
#define NPTS   512
#define CPB    64          // chunks (blocks) per batch in reduce kernel
#define HSLOTS 8192        // LDS hash slots (64 KB total)

__device__ __forceinline__ float waveReduceSum(float v) {
    for (int o = 32; o > 0; o >>= 1) v += __shfl_down(v, o);
    return v;
}

// K1: per-batch sum(pred) and sum(pred^2). Grid = NB*CPB blocks x 256 threads.
// Each block handles HWSZ/CPB = 4096 contiguous floats (1024 float4, 4 iters).
__global__ __launch_bounds__(256)
void k_reduce(const float* __restrict__ pred, float* __restrict__ S, float* __restrict__ P2) {
    int b = blockIdx.x >> 6;       // / CPB
    int c = blockIdx.x & (CPB - 1);
    const float4* base = (const float4*)(pred + (size_t)b * HWSZ + (size_t)c * (HWSZ / CPB));
    float s = 0.f, q = 0.f;
#pragma unroll
    for (int i = 0; i < 4; ++i) {
        float4 v = base[threadIdx.x + i * 256];
        s += (v.x + v.y) + (v.z + v.w);
        q += v.x * v.x + v.y * v.y + v.z * v.z + v.w * v.w;
    }
    s = waveReduceSum(s);
    q = waveReduceSum(q);
    __shared__ float ls[4], lq[4];
    int wave = threadIdx.x >> 6, lane = threadIdx.x & 63;
    if (lane == 0) { ls[wave] = s; lq[wave] = q; }
    __syncthreads();
    if (threadIdx.x == 0) {
        atomicAdd(&S[b],  (ls[0] + ls[1]) + (ls[2] + ls[3]));
        atomicAdd(&P2[b], (lq[0] + lq[1]) + (lq[2] + lq[3]));
    }
}

// K2: per-batch sparse scatter with dedup via LDS hash.
// One block (512 threads) per batch. Produces:
//   TS[b]  = sum of valid weights (tsum)
//   T2[b]  = sum over cells of (aggregated weight)^2
//   DOT[b] = sum over cells of aggregated_weight * pred[cell]
__global__ __launch_bounds__(512)
void k_scatter(const float* __restrict__ pred, const float* __restrict__ points,
               const int* __restrict__ pHin, const int* __restrict__ pWin,
               float* __restrict__ T2, float* __restrict__ DOT, float* __restrict__ TS) {
    __shared__ unsigned keys[HSLOTS];
    __shared__ float    vals[HSLOTS];
    const int b = blockIdx.x;
    for (int i = threadIdx.x; i < HSLOTS; i += 512) { keys[i] = 0xFFFFFFFFu; vals[i] = 0.f; }
    __syncthreads();

    const float scale_w = (float)WW / (float)(*pWin);
    const float scale_h = (float)HH / (float)(*pHin);
    const float wEdge = expf(-0.5f);
    const float wDiag = expf(-0.70710678118654752440f);  // exp(-sqrt(2)/2)

    float wsum = 0.f;
    for (int p = threadIdx.x; p < NPTS; p += 512) {
        float px = points[((size_t)b * NPTS + p) * 2 + 0];
        float py = points[((size_t)b * NPTS + p) * 2 + 1];
        int x = (int)fminf(fmaxf(px * scale_w, 0.f), (float)(WW - 1));
        int y = (int)fminf(fmaxf(py * scale_h, 0.f), (float)(HH - 1));
#pragma unroll
        for (int dy = -1; dy <= 1; ++dy)
#pragma unroll
            for (int dx = -1; dx <= 1; ++dx) {
                int ny = y + dy, nx = x + dx;
                if (ny < 0 || ny >= HH || nx < 0 || nx >= WW) continue;
                int d2 = dy * dy + dx * dx;
                float w = (d2 == 0) ? 1.f : ((d2 == 1) ? wEdge : wDiag);
                wsum += w;
                unsigned key = (unsigned)(ny * WW + nx);
                unsigned h = (key * 2654435761u) >> 19;   // top 13 bits -> [0,8192)
                for (;;) {
                    unsigned old = atomicCAS(&keys[h], 0xFFFFFFFFu, key);
                    if (old == 0xFFFFFFFFu || old == key) { atomicAdd(&vals[h], w); break; }
                    h = (h + 1) & (HSLOTS - 1);
                }
            }
    }
    __syncthreads();

    float t2 = 0.f, dot = 0.f;
    const float* pb = pred + (size_t)b * HWSZ;
    for (int i = threadIdx.x; i < HSLOTS; i += 512) {
        unsigned key = keys[i];
        if (key != 0xFFFFFFFFu) {
            float t = vals[i];
            t2  += t * t;
            dot += t * pb[key];
        }
    }

    wsum = waveReduceSum(wsum);
    t2   = waveReduceSum(t2);
    dot  = waveReduceSum(dot);
    __syncthreads();                       // done reading vals; safe to reuse as scratch
    int wave = threadIdx.x >> 6, lane = threadIdx.x & 63;   // 8 waves
    if (lane == 0) { vals[wave] = wsum; vals[8 + wave] = t2; vals[16 + wave] = dot; }
    __syncthreads();
    if (threadIdx.x == 0) {
        float a0 = 0.f, a1 = 0.f, a2 = 0.f;
        for (int wv = 0; wv < 8; ++wv) { a0 += vals[wv]; a1 += vals[8 + wv]; a2 += vals[16 + wv]; }
        TS[b] = a0; T2[b] = a1; DOT[b] = a2;
    }
}

// K3: finalize (single wave). f64 accumulation.
__global__ __launch_bounds__(64)
void k_final(const float* __restrict__ S, const float* __restrict__ P2,
             const float* __restrict__ T2, const float* __restrict__ DOT,
             const float* __restrict__ TS, const int* __restrict__ pCell,
             float* __restrict__ out) {
    int t = threadIdx.x;
    double cl = 0.0, sl = 0.0;
    if (t < NB) {
        double s = (double)S[t];
        cl = fabs(s / (double)(*pCell) - (double)NPTS);
        double sn = s + 1e-8;
        double ts = (double)TS[t];
        double term = (double)P2[t] / (sn * sn)
                    - 2.0 * (double)DOT[t] / (sn * ts)
                    + (double)T2[t] / (ts * ts);
        sl = term / (double)HWSZ;
    }
    for (int o = 32; o > 0; o >>= 1) { cl += __shfl_down(cl, o); sl += __shfl_down(sl, o); }
    if (t == 0) {
        double count_loss   = cl / (double)NB;
        double spatial_loss = sl / (double)NB;
        double total = 2.5 * count_loss + 0.1 * spatial_loss;  // scale_loss == 0
        out[0] = (float)total;
        out[1] = (float)count_loss;
        out[2] = (float)spatial_loss;
    }
}

extern "C" void kernel_launch(void* const* d_in, const int* in_sizes, int n_in,
                              void* d_out, int out_size, void* d_ws, size_t ws_size,
                              hipStream_t stream) {
    const float* pred   = (const float*)d_in[0];
    const float* points = (const float*)d_in[1];
    const int*   cell   = (const int*)d_in[2];
    const int*   hin    = (const int*)d_in[3];
    const int*   win    = (const int*)d_in[4];
    float* out = (float*)d_out;

    float* S   = (float*)d_ws;      // NB floats (atomic targets — must be zeroed)
    float* P2  = S + NB;            // NB floats (atomic targets — must be zeroed)
    float* T2  = S + 2 * NB;        // written unconditionally by k_scatter
    float* DOT = S + 3 * NB;
    float* TS  = S + 4 * NB;

    hipMemsetAsync(S, 0, 2 * NB * sizeof(float), stream);
    k_reduce<<<NB * CPB, 256, 0, stream>>>(pred, S, P2);
    k_scatter<<<NB, 512, 0, stream>>>(pred, points, hin, win, T2, DOT, TS);
    k_final<<<1, 64, 0, stream>>>(S, P2, T2, DOT, TS, cell, out);
}

// Round 2
// 111.850 us; speedup vs baseline: 1.2861x; 1.2861x over previous
//
#include <hip/hip_runtime.h>

#define NB     64          // batch
#define HH     512
#define WW     512
#define HWSZ   (HH * WW)   // 262144 floats per batch image
#define NPTS   512
#define RBPB   4           // reduce blocks per batch
#define NRB    (NB * RBPB) // 256 reduce-role blocks
#define HSLOTS 8192        // LDS hash slots (64 KB total)

__device__ __forceinline__ float waveReduceSum(float v) {
    for (int o = 32; o > 0; o >>= 1) v += __shfl_down(v, o);
    return v;
}

// Fused kernel. Grid = NB + NRB = 320 blocks x 512 threads.
//  blocks [0, NB)        : scatter role — per-batch sparse target via LDS hash
//                          -> TS[b] (weight sum), T2[b] (sum t^2), DOT[b] (sum t*pred)
//  blocks [NB, NB+NRB)   : reduce role — rb-th quarter-batch chunk of pred
//                          -> Spart[rb] (sum), P2part[rb] (sum of squares)
// All ws outputs written unconditionally (d_ws is poisoned before every launch).
__global__ __launch_bounds__(512)
void k_fused(const float* __restrict__ pred, const float* __restrict__ points,
             const int* __restrict__ pHin, const int* __restrict__ pWin,
             float* __restrict__ Spart, float* __restrict__ P2part,
             float* __restrict__ T2, float* __restrict__ DOT, float* __restrict__ TS) {
    __shared__ unsigned keys[HSLOTS];
    __shared__ float    vals[HSLOTS];
    const int tid = threadIdx.x;

    if (blockIdx.x >= NB) {
        // ---------------- reduce role ----------------
        const int rb = blockIdx.x - NB;                       // 0..255
        // contiguous chunk: floats [rb*HWSZ/RBPB, ...) == float4 [rb*16384, ...)
        const float4* base = (const float4*)pred + (size_t)rb * (HWSZ / RBPB / 4);
        float s = 0.f, q = 0.f;
#pragma unroll
        for (int i = 0; i < 32; ++i) {                        // 32*512 = 16384 float4
            float4 v = base[tid + i * 512];
            s += (v.x + v.y) + (v.z + v.w);
            q += v.x * v.x + v.y * v.y + v.z * v.z + v.w * v.w;
        }
        s = waveReduceSum(s);
        q = waveReduceSum(q);
        const int wave = tid >> 6, lane = tid & 63;
        if (lane == 0) { vals[wave] = s; vals[8 + wave] = q; }
        __syncthreads();
        if (tid == 0) {
            float a = 0.f, b2 = 0.f;
            for (int w = 0; w < 8; ++w) { a += vals[w]; b2 += vals[8 + w]; }
            Spart[rb] = a; P2part[rb] = b2;
        }
        return;
    }

    // ---------------- scatter role ----------------
    const int b = blockIdx.x;
    for (int i = tid; i < HSLOTS; i += 512) { keys[i] = 0xFFFFFFFFu; vals[i] = 0.f; }
    __syncthreads();

    const float scale_w = (float)WW / (float)(*pWin);
    const float scale_h = (float)HH / (float)(*pHin);
    const float wEdge = expf(-0.5f);
    const float wDiag = expf(-0.70710678118654752440f);       // exp(-sqrt(2)/2)

    float wsum = 0.f;
    {
        // one point per thread (NPTS == blockDim)
        const float2 pt = ((const float2*)points)[(size_t)b * NPTS + tid];
        int x = (int)fminf(fmaxf(pt.x * scale_w, 0.f), (float)(WW - 1));
        int y = (int)fminf(fmaxf(pt.y * scale_h, 0.f), (float)(HH - 1));
#pragma unroll
        for (int dy = -1; dy <= 1; ++dy)
#pragma unroll
            for (int dx = -1; dx <= 1; ++dx) {
                int ny = y + dy, nx = x + dx;
                if (ny < 0 || ny >= HH || nx < 0 || nx >= WW) continue;
                int d2 = dy * dy + dx * dx;
                float w = (d2 == 0) ? 1.f : ((d2 == 1) ? wEdge : wDiag);
                wsum += w;
                unsigned key = (unsigned)(ny * WW + nx);
                unsigned h = (key * 2654435761u) >> 19;       // top 13 bits -> [0,8192)
                for (;;) {
                    unsigned old = atomicCAS(&keys[h], 0xFFFFFFFFu, key);
                    if (old == 0xFFFFFFFFu || old == key) { atomicAdd(&vals[h], w); break; }
                    h = (h + 1) & (HSLOTS - 1);
                }
            }
    }
    __syncthreads();

    float t2 = 0.f, dot = 0.f;
    const float* pb = pred + (size_t)b * HWSZ;
    for (int i = tid; i < HSLOTS; i += 512) {
        unsigned key = keys[i];
        if (key != 0xFFFFFFFFu) {
            float t = vals[i];
            t2  += t * t;
            dot += t * pb[key];
        }
    }

    wsum = waveReduceSum(wsum);
    t2   = waveReduceSum(t2);
    dot  = waveReduceSum(dot);
    __syncthreads();                 // done reading vals; reuse as scratch
    const int wave = tid >> 6, lane = tid & 63;
    if (lane == 0) { vals[wave] = wsum; vals[8 + wave] = t2; vals[16 + wave] = dot; }
    __syncthreads();
    if (tid == 0) {
        float a0 = 0.f, a1 = 0.f, a2 = 0.f;
        for (int w = 0; w < 8; ++w) { a0 += vals[w]; a1 += vals[8 + w]; a2 += vals[16 + w]; }
        TS[b] = a0; T2[b] = a1; DOT[b] = a2;
    }
}

// Finalize: single wave, f64 accumulation.
__global__ __launch_bounds__(64)
void k_final(const float* __restrict__ Spart, const float* __restrict__ P2part,
             const float* __restrict__ T2, const float* __restrict__ DOT,
             const float* __restrict__ TS, const int* __restrict__ pCell,
             float* __restrict__ out) {
    int t = threadIdx.x;
    double cl = 0.0, sl = 0.0;
    if (t < NB) {
        double s = 0.0, p2 = 0.0;
#pragma unroll
        for (int c = 0; c < RBPB; ++c) {
            s  += (double)Spart[t * RBPB + c];
            p2 += (double)P2part[t * RBPB + c];
        }
        cl = fabs(s / (double)(*pCell) - (double)NPTS);
        double sn = s + 1e-8;
        double ts = (double)TS[t];
        double term = p2 / (sn * sn)
                    - 2.0 * (double)DOT[t] / (sn * ts)
                    + (double)T2[t] / (ts * ts);
        sl = term / (double)HWSZ;
    }
    for (int o = 32; o > 0; o >>= 1) { cl += __shfl_down(cl, o); sl += __shfl_down(sl, o); }
    if (t == 0) {
        double count_loss   = cl / (double)NB;
        double spatial_loss = sl / (double)NB;
        double total = 2.5 * count_loss + 0.1 * spatial_loss;   // scale_loss == 0
        out[0] = (float)total;
        out[1] = (float)count_loss;
        out[2] = (float)spatial_loss;
    }
}

extern "C" void kernel_launch(void* const* d_in, const int* in_sizes, int n_in,
                              void* d_out, int out_size, void* d_ws, size_t ws_size,
                              hipStream_t stream) {
    const float* pred   = (const float*)d_in[0];
    const float* points = (const float*)d_in[1];
    const int*   cell   = (const int*)d_in[2];
    const int*   hin    = (const int*)d_in[3];
    const int*   win    = (const int*)d_in[4];
    float* out = (float*)d_out;

    float* Spart  = (float*)d_ws;        // NRB floats
    float* P2part = Spart + NRB;         // NRB floats
    float* T2     = Spart + 2 * NRB;     // NB floats
    float* DOT    = T2 + NB;
    float* TS     = DOT + NB;

    k_fused<<<NB + NRB, 512, 0, stream>>>(pred, points, hin, win,
                                          Spart, P2part, T2, DOT, TS);
    k_final<<<1, 64, 0, stream>>>(Spart, P2part, T2, DOT, TS, cell, out);
}